// Round 4
// baseline (410.376 us; speedup 1.0000x reference)
//
#include <hip/hip_runtime.h>
#include <hip/hip_bf16.h>
#include <cstdint>

// MHD PINN loss, fully fused + persistent. N=131072 pts, H=256.
// Swapped-operand: D = W * X^T (m = neuron, n = 16 pts x 4 streams).
// Block = 512 thr (8 waves); GRID = 512 -> 2 blocks/CU (independent barriers
// so one block's MFMA overlaps the other's VALU/LDS/barrier phases),
// 4 waves/SIMD at VGPR<=128. Each wave owns 32 output neurons; its W2/W3
// slices live in registers. Streams: s=0 h, s=1..3 d/dx,d/dy,d/dt.

#define LDW 264   // X tile row stride in ushorts
#define TPTS 16
#define GRIDB 512

typedef __attribute__((ext_vector_type(8))) short v8h;   // 8 x bf16
typedef __attribute__((ext_vector_type(4))) float v4f;

__device__ __forceinline__ ushort f2b(float f) {           // fp32 -> bf16 RNE
    uint32_t u = __float_as_uint(f);
    u = (u + 0x7fffu + ((u >> 16) & 1u)) >> 16;
    return (ushort)u;
}
__device__ __forceinline__ uint32_t pk2(float a, float b) { // v_cvt_pk_bf16_f32
    union { __hip_bfloat162 h2; uint32_t u; } cv;
    cv.h2 = __float22bfloat162_rn(make_float2(a, b));
    return cv.u;
}
__device__ __forceinline__ float fast_tanh(float x) {
    float e = __expf(2.0f * x);
    return 1.0f - 2.0f * __builtin_amdgcn_rcpf(e + 1.0f);
}

// prep: W2,W3 (256x256 [k][n]) -> bf16 transposed Wt[n][k]; W4 (256x6) -> Wt4[16][256] padded
__global__ void prep_weights(const float* __restrict__ W2, const float* __restrict__ W3,
                             const float* __restrict__ W4,
                             ushort* __restrict__ Wt2, ushort* __restrict__ Wt3,
                             ushort* __restrict__ Wt4) {
    int idx = blockIdx.x * 256 + threadIdx.x;
    if (idx < 65536) {
        int k = idx >> 8, n = idx & 255;
        Wt2[n * 256 + k] = f2b(W2[k * 256 + n]);
        Wt3[n * 256 + k] = f2b(W3[k * 256 + n]);
    }
    if (idx < 4096) {
        int n = idx >> 8, k = idx & 255;
        Wt4[n * 256 + k] = (n < 6) ? f2b(W4[k * 6 + n]) : (ushort)0;
    }
}

// one hidden layer: D = W(32x256 slice) * src^T(256x64); src -> dst (ping-pong)
__device__ __forceinline__ void dense_layer(const ushort* __restrict__ src,
                                            ushort* __restrict__ dst,
                                            const v8h (*wf)[8], const v4f* bs,
                                            int wv, int q, int l15) {
    v4f acc[2][4];
    #pragma unroll
    for (int a = 0; a < 2; a++)
        #pragma unroll
        for (int b = 0; b < 4; b++) {
            v4f z = {0.0f, 0.0f, 0.0f, 0.0f};
            acc[a][b] = z;
        }
    #pragma unroll
    for (int kk = 0; kk < 8; kk++) {
        v8h B[4];
        #pragma unroll
        for (int nt = 0; nt < 4; nt++)
            B[nt] = *(const v8h*)(&src[(nt * 16 + l15) * LDW + kk * 32 + q * 8]);
        #pragma unroll
        for (int mt = 0; mt < 2; mt++)
            #pragma unroll
            for (int nt = 0; nt < 4; nt++)
                acc[mt][nt] = __builtin_amdgcn_mfma_f32_16x16x32_bf16(wf[mt][kk], B[nt], acc[mt][nt], 0, 0, 0);
    }
    // D row (neuron) = mt*16 + q*4 + r, D col = nt*16 + l15 => stream s = nt, point p = l15.
    #pragma unroll
    for (int mt = 0; mt < 2; mt++) {
        const int colb = wv * 32 + mt * 16 + q * 4;
        v4f bb = bs[mt];
        float h0 = fast_tanh(acc[mt][0][0] + bb[0]);
        float h1 = fast_tanh(acc[mt][0][1] + bb[1]);
        float h2 = fast_tanh(acc[mt][0][2] + bb[2]);
        float h3 = fast_tanh(acc[mt][0][3] + bb[3]);
        float d0 = 1.0f - h0 * h0, d1 = 1.0f - h1 * h1;
        float d2 = 1.0f - h2 * h2, d3 = 1.0f - h3 * h3;
        uint2 w;
        w.x = pk2(h0, h1); w.y = pk2(h2, h3);
        *(uint2*)(&dst[l15 * LDW + colb]) = w;
        #pragma unroll
        for (int s = 1; s < 4; s++) {
            w.x = pk2(d0 * acc[mt][s][0], d1 * acc[mt][s][1]);
            w.y = pk2(d2 * acc[mt][s][2], d3 * acc[mt][s][3]);
            *(uint2*)(&dst[(s * 16 + l15) * LDW + colb]) = w;
        }
    }
}

__global__ __launch_bounds__(512, 4)
void mhd_fused(const float* __restrict__ coords,
               const float* __restrict__ W1, const float* __restrict__ b1,
               const float* __restrict__ b2, const float* __restrict__ b3,
               const float* __restrict__ b4,
               const float* __restrict__ wts,
               const ushort* __restrict__ Wt2, const ushort* __restrict__ Wt3,
               const ushort* __restrict__ Wt4,
               float* __restrict__ out, int npts, float inv_n) {
    __shared__ ushort Xs0[64 * LDW];
    __shared__ ushort Xs1[64 * LDW];
    __shared__ ushort W4s[16 * LDW];
    __shared__ float  cs[TPTS * 3];
    __shared__ float  Y4[4][TPTS][8];

    const int tid  = threadIdx.x;
    const int lane = tid & 63;
    const int wv   = tid >> 6;      // 0..7
    const int q    = lane >> 4;
    const int l15  = lane & 15;

    // ---- stage W4 (16x256, padded) into LDS ----------------------------------
    for (int idx = tid; idx < 16 * 256; idx += 512)
        W4s[(idx >> 8) * LDW + (idx & 255)] = Wt4[idx];

    // ---- weight fragments -> registers (wave owns 32 neurons) ----------------
    v8h w2f[2][8], w3f[2][8];
    v4f bs2[2], bs3[2];
    #pragma unroll
    for (int mt = 0; mt < 2; mt++) {
        const int nrow = (wv * 32 + mt * 16 + l15) * 256 + q * 8;
        #pragma unroll
        for (int kk = 0; kk < 8; kk++) {
            w2f[mt][kk] = *(const v8h*)(&Wt2[nrow + kk * 32]);
            w3f[mt][kk] = *(const v8h*)(&Wt3[nrow + kk * 32]);
        }
        bs2[mt] = *(const v4f*)(&b2[wv * 32 + mt * 16 + q * 4]);
        bs3[mt] = *(const v4f*)(&b3[wv * 32 + mt * 16 + q * 4]);
    }

    // L1 thread mapping: col pair (2*cp, 2*cp+1), point group pg (4 pts each)
    const int cp = tid & 127, pg = tid >> 7;
    const float b40 = b4[0], b41 = b4[1], b42 = b4[2], b43 = b4[3], b44 = b4[4], b45 = b4[5];
    const float wt0 = wts[0], wt1 = wts[1], wt2_ = wts[2], wt3_ = wts[3],
                wt4_ = wts[4], wt5 = wts[5], wt6 = wts[6];

    const int ntiles = (npts + TPTS - 1) / TPTS;
    float vsum = 0.0f;

    for (int tile = blockIdx.x; tile < ntiles; tile += GRIDB) {
        const int base = tile * TPTS;

        if (tid < TPTS * 3) {
            int p = tid / 3, c = tid % 3;
            int gp = base + p; if (gp >= npts) gp = npts - 1;
            cs[tid] = coords[gp * 3 + c];
        }
        __syncthreads();   // B1: cs ready; prev tile's Xs0/Y4 readers done

        // ---- layer 1 (3->256): thread handles cols {2cp,2cp+1} x 4 points ----
        {
            const int j0 = cp * 2;
            float wa0 = W1[j0],       wb0 = W1[j0 + 1];
            float wa1 = W1[256 + j0], wb1 = W1[257 + j0];
            float wa2 = W1[512 + j0], wb2 = W1[513 + j0];
            float ba  = b1[j0],       bb  = b1[j0 + 1];
            #pragma unroll
            for (int pp = 0; pp < 4; pp++) {
                const int p = pg * 4 + pp;
                float x = cs[p * 3], y = cs[p * 3 + 1], t = cs[p * 3 + 2];
                float ha = fast_tanh(fmaf(x, wa0, fmaf(y, wa1, fmaf(t, wa2, ba))));
                float hb = fast_tanh(fmaf(x, wb0, fmaf(y, wb1, fmaf(t, wb2, bb))));
                float da = 1.0f - ha * ha, db = 1.0f - hb * hb;
                *(uint32_t*)(&Xs0[p * LDW + j0])        = pk2(ha, hb);
                *(uint32_t*)(&Xs0[(16 + p) * LDW + j0]) = pk2(da * wa0, db * wb0);
                *(uint32_t*)(&Xs0[(32 + p) * LDW + j0]) = pk2(da * wa1, db * wb1);
                *(uint32_t*)(&Xs0[(48 + p) * LDW + j0]) = pk2(da * wa2, db * wb2);
            }
        }
        __syncthreads();   // B2

        dense_layer(Xs0, Xs1, w2f, bs2, wv, q, l15);   // L2: A -> B
        __syncthreads();   // B3
        dense_layer(Xs1, Xs0, w3f, bs3, wv, q, l15);   // L3: B -> A
        __syncthreads();   // B4

        // ---- layer 4: waves 0..3 handle stream wv ----------------------------
        if (wv < 4) {
            v4f a4 = {0.0f, 0.0f, 0.0f, 0.0f};
            #pragma unroll
            for (int kk = 0; kk < 8; kk++) {
                v8h A = *(const v8h*)(&W4s[l15 * LDW + kk * 32 + q * 8]);
                v8h B = *(const v8h*)(&Xs0[(wv * 16 + l15) * LDW + kk * 32 + q * 8]);
                a4 = __builtin_amdgcn_mfma_f32_16x16x32_bf16(A, B, a4, 0, 0, 0);
            }
            if (q < 2) {
                #pragma unroll
                for (int r = 0; r < 4; r++)
                    Y4[wv][l15][q * 4 + r] = a4[r];
            }
        }
        __syncthreads();   // B5: Y4 ready

        // ---- residuals: wave-0 threads 0..15, one point each ------------------
        if (tid < 16 && (base + tid) < npts) {
            const float* Yh = Y4[0][tid];
            const float* JX = Y4[1][tid];
            const float* JY = Y4[2][tid];
            const float* JT = Y4[3][tid];
            const float g1 = 1.5f;
            float rho = Yh[0] + b40, vx = Yh[1] + b41, vy = Yh[2] + b42;
            float Bx  = Yh[3] + b43, By = Yh[4] + b44, P  = Yh[5] + b45;
            float v2 = vx * vx + vy * vy;
            float dt_rho = JT[0];
            float dt_rhovx = dt_rho * vx + rho * JT[1];
            float dt_rhovy = dt_rho * vy + rho * JT[2];
            auto dE = [&](const float* J) {
                return J[5] * g1 + 0.5f * J[0] * v2 + rho * (vx * J[1] + vy * J[2]) + Bx * J[3] + By * J[4];
            };
            float dE_dx = dE(JX), dE_dy = dE(JY), dE_dt = dE(JT);
            float div_v = JX[1] + JY[2];
            float div_B = JX[3] + JY[4];
            float continuity = dt_rho + rho * div_v;
            float dPm_dx = JX[5] + Bx * JX[3] + By * JX[4];
            float dPm_dy = JY[5] + Bx * JY[3] + By * JY[4];
            float momentum_x = dt_rhovx + dPm_dx - (Bx * JX[3] + By * JY[3]);
            float momentum_y = dt_rhovy + dPm_dy - (Bx * JX[4] + By * JY[4]);
            auto dG = [&](const float* J) {
                return J[1] * By + vx * J[4] - J[2] * Bx - vy * J[3];
            };
            float induction_x = JT[3] + dG(JY);
            float induction_y = JT[4] - dG(JX);
            float E = P * g1 + 0.5f * rho * v2 + 0.5f * (Bx * Bx + By * By);
            float S = E + P + 0.5f * (Bx * Bx + By * By);
            float dS_dx = dE_dx + JX[5] + Bx * JX[3] + By * JX[4];
            float dS_dy = dE_dy + JY[5] + Bx * JY[3] + By * JY[4];
            float D = Bx * vx + By * vy;
            auto dD = [&](const float* J) {
                return J[3] * vx + Bx * J[1] + J[4] * vy + By * J[2];
            };
            float dFx_dx = dS_dx * vx + S * JX[1] - dD(JX) * Bx - D * JX[3];
            float dFy_dy = dS_dy * vy + S * JY[2] - dD(JY) * By - D * JY[4];
            float energy = dE_dt + dFx_dx + dFy_dy;
            vsum += wt0 * continuity * continuity
                  + wt1 * momentum_x * momentum_x
                  + wt2_ * momentum_y * momentum_y
                  + wt3_ * induction_x * induction_x
                  + wt4_ * induction_y * induction_y
                  + wt5 * energy * energy
                  + wt6 * div_B * div_B;
        }
        // next-iter B1 orders Y4/cs/Xs0 reuse (residual & cs both wave 0)
    }

    if (tid < 64) {
        #pragma unroll
        for (int off = 8; off >= 1; off >>= 1)
            vsum += __shfl_down(vsum, off, 64);
        if (tid == 0) atomicAdd(out, vsum * inv_n);
    }
}

extern "C" void kernel_launch(void* const* d_in, const int* in_sizes, int n_in,
                              void* d_out, int out_size, void* d_ws, size_t ws_size,
                              hipStream_t stream) {
    const float* coords = (const float*)d_in[0];
    const float* W1 = (const float*)d_in[1];
    const float* b1 = (const float*)d_in[2];
    const float* W2 = (const float*)d_in[3];
    const float* b2 = (const float*)d_in[4];
    const float* W3 = (const float*)d_in[5];
    const float* b3 = (const float*)d_in[6];
    const float* W4 = (const float*)d_in[7];
    const float* b4 = (const float*)d_in[8];
    const float* wts = (const float*)d_in[9];
    const int npts = in_sizes[0] / 3;

    ushort* Wt2 = (ushort*)d_ws;
    ushort* Wt3 = Wt2 + 65536;
    ushort* Wt4 = Wt3 + 65536;

    hipMemsetAsync(d_out, 0, sizeof(float), stream);
    prep_weights<<<256, 256, 0, stream>>>(W2, W3, W4, Wt2, Wt3, Wt4);
    mhd_fused<<<GRIDB, 512, 0, stream>>>(coords, W1, b1, b2, b3, b4, wts,
                                         Wt2, Wt3, Wt4, (float*)d_out, npts, 1.0f / npts);
}

// Round 7
// 322.065 us; speedup vs baseline: 1.2742x; 1.2742x over previous
//
#include <hip/hip_runtime.h>
#include <hip/hip_bf16.h>
#include <cstdint>

// MHD PINN loss, fused persistent bf16. N=131072, H=256.
// D = W * X^T (m=neuron, n=16pts x 4 streams). Block=512 (8 waves), grid=256,
// 1 block/CU, 2 waves/SIMD; each wave holds its 32-neuron W2/W3 slices in regs.
// Software-pipelined tile loop (3 barriers): phase0 = residual(t-2)+L1(t+1),
// then L2 -> B -> L3 -> B -> L4. LDS XOR-swizzled (16B chunk ^ row) to kill
// bank conflicts; no padding (row stride 512 B).

#define GRIDB 256
#define TPTS 16

typedef __attribute__((ext_vector_type(8))) short v8h;   // 8 x bf16
typedef __attribute__((ext_vector_type(4))) float v4f;

__device__ __forceinline__ ushort f2b(float f) {
    uint32_t u = __float_as_uint(f);
    u = (u + 0x7fffu + ((u >> 16) & 1u)) >> 16;
    return (ushort)u;
}
__device__ __forceinline__ uint32_t pk2(float a, float b) { // v_cvt_pk_bf16_f32
    union { __hip_bfloat162 h2; uint32_t u; } cv;
    cv.h2 = __float22bfloat162_rn(make_float2(a, b));
    return cv.u;
}
__device__ __forceinline__ float fast_tanh(float x) {
    float e = __expf(2.0f * x);
    return 1.0f - 2.0f * __builtin_amdgcn_rcpf(e + 1.0f);
}
// swizzled LDS byte address: row stride 512 B, 16-B chunk XOR with row
__device__ __forceinline__ int swz(int row, int bytecol) {
    return (row << 9) + ((((bytecol >> 4) ^ (row & 31)) << 4) | (bytecol & 15));
}

// prep: W2,W3 (256x256 [k][n]) -> bf16 transposed Wt[n][k]; W4 (256x6) -> Wt4[16][256]
__global__ void prep_weights(const float* __restrict__ W2, const float* __restrict__ W3,
                             const float* __restrict__ W4,
                             ushort* __restrict__ Wt2, ushort* __restrict__ Wt3,
                             ushort* __restrict__ Wt4) {
    int idx = blockIdx.x * 256 + threadIdx.x;
    if (idx < 65536) {
        int k = idx >> 8, n = idx & 255;
        Wt2[n * 256 + k] = f2b(W2[k * 256 + n]);
        Wt3[n * 256 + k] = f2b(W3[k * 256 + n]);
    }
    if (idx < 4096) {
        int n = idx >> 8, k = idx & 255;
        Wt4[n * 256 + k] = (n < 6) ? f2b(W4[k * 6 + n]) : (ushort)0;
    }
}

__global__ __launch_bounds__(512, 2)
void mhd_fused(const float* __restrict__ coords,
               const float* __restrict__ W1, const float* __restrict__ b1,
               const float* __restrict__ b2, const float* __restrict__ b3,
               const float* __restrict__ b4,
               const float* __restrict__ wts,
               const ushort* __restrict__ Wt2, const ushort* __restrict__ Wt3,
               const ushort* __restrict__ Wt4,
               float* __restrict__ out, int npts, float inv_n) {
    __shared__ __align__(16) uint8_t XinB[2][64 * 512];
    __shared__ __align__(16) uint8_t Xmid[64 * 512];
    __shared__ __align__(16) uint8_t Xout[64 * 512];
    __shared__ __align__(16) uint8_t W4s[16 * 512];
    __shared__ float Y4[2][4][TPTS][8];

    const int tid  = threadIdx.x;
    const int lane = tid & 63;
    const int wv   = tid >> 6;      // 0..7
    const int q    = lane >> 4;
    const int l15  = lane & 15;

    // ---- stage W4 (16x256 bf16) into swizzled LDS ----------------------------
    for (int idx = tid; idx < 16 * 128; idx += 512) {     // dword units
        int n = idx >> 7, kdw = idx & 127;
        *(uint32_t*)(&W4s[(n << 9) + ((((kdw >> 2) ^ n) << 4) | ((kdw & 3) << 2))]) =
            ((const uint32_t*)Wt4)[idx];
    }

    // ---- W2/W3 fragments -> registers (wave owns 32 neurons) -----------------
    v8h w2f[2][8], w3f[2][8];
    v4f bs2[2], bs3[2];
    #pragma unroll
    for (int mt = 0; mt < 2; mt++) {
        const int nrow = (wv * 32 + mt * 16 + l15) * 256 + q * 8;
        #pragma unroll
        for (int kk = 0; kk < 8; kk++) {
            w2f[mt][kk] = *(const v8h*)(&Wt2[nrow + kk * 32]);
            w3f[mt][kk] = *(const v8h*)(&Wt3[nrow + kk * 32]);
        }
        bs2[mt] = *(const v4f*)(&b2[wv * 32 + mt * 16 + q * 4]);
        bs3[mt] = *(const v4f*)(&b3[wv * 32 + mt * 16 + q * 4]);
    }

    // ---- L1 constants: thread owns cols j0..j0+3, points pg*2, pg*2+1 --------
    const int j0 = (tid & 63) * 4, pg = tid >> 6;
    float l1w0[4], l1w1[4], l1w2[4], l1b[4];
    #pragma unroll
    for (int c = 0; c < 4; c++) {
        l1w0[c] = W1[j0 + c]; l1w1[c] = W1[256 + j0 + c];
        l1w2[c] = W1[512 + j0 + c]; l1b[c] = b1[j0 + c];
    }

    const float b40 = b4[0], b41 = b4[1], b42 = b4[2], b43 = b4[3], b44 = b4[4], b45 = b4[5];
    const float wt0 = wts[0], wt1 = wts[1], wt2_ = wts[2], wt3_ = wts[3],
                wt4_ = wts[4], wt5 = wts[5], wt6 = wts[6];

    // ---- L1: 3->256 + tangent seeds, into swizzled Xin buffer ----------------
    auto do_l1 = [&](int tile, uint8_t* Xin) {
        const int base = tile * TPTS;
        #pragma unroll
        for (int pp = 0; pp < 2; pp++) {
            const int p = pg * 2 + pp;
            int gp = base + p; if (gp >= npts) gp = npts - 1;
            float x = coords[gp * 3], y = coords[gp * 3 + 1], t = coords[gp * 3 + 2];
            float h[4], d[4];
            #pragma unroll
            for (int c = 0; c < 4; c++) {
                h[c] = fast_tanh(fmaf(x, l1w0[c], fmaf(y, l1w1[c], fmaf(t, l1w2[c], l1b[c]))));
                d[c] = 1.0f - h[c] * h[c];
            }
            uint2 w;
            const int bc = j0 * 2;
            w.x = pk2(h[0], h[1]); w.y = pk2(h[2], h[3]);
            *(uint2*)(&Xin[swz(p, bc)]) = w;
            w.x = pk2(d[0] * l1w0[0], d[1] * l1w0[1]); w.y = pk2(d[2] * l1w0[2], d[3] * l1w0[3]);
            *(uint2*)(&Xin[swz(16 + p, bc)]) = w;
            w.x = pk2(d[0] * l1w1[0], d[1] * l1w1[1]); w.y = pk2(d[2] * l1w1[2], d[3] * l1w1[3]);
            *(uint2*)(&Xin[swz(32 + p, bc)]) = w;
            w.x = pk2(d[0] * l1w2[0], d[1] * l1w2[1]); w.y = pk2(d[2] * l1w2[2], d[3] * l1w2[3]);
            *(uint2*)(&Xin[swz(48 + p, bc)]) = w;
        }
    };

    // ---- hidden layer: D = W(32x256) * src^T(256x64), src -> dst -------------
    auto dense = [&](const uint8_t* src, uint8_t* dst, const v8h (*wf)[8], const v4f* bs) {
        v4f acc[2][4];
        #pragma unroll
        for (int a = 0; a < 2; a++)
            #pragma unroll
            for (int b = 0; b < 4; b++) {
                v4f z = {0.0f, 0.0f, 0.0f, 0.0f};
                acc[a][b] = z;
            }
        #pragma unroll
        for (int kk = 0; kk < 8; kk++) {
            v8h B[4];
            #pragma unroll
            for (int nt = 0; nt < 4; nt++) {
                const int row = nt * 16 + l15;
                B[nt] = *(const v8h*)(&src[(row << 9) + ((((kk * 4 + q) ^ (row & 31)) << 4))]);
            }
            #pragma unroll
            for (int mt = 0; mt < 2; mt++)
                #pragma unroll
                for (int nt = 0; nt < 4; nt++)
                    acc[mt][nt] = __builtin_amdgcn_mfma_f32_16x16x32_bf16(wf[mt][kk], B[nt], acc[mt][nt], 0, 0, 0);
        }
        // D row (neuron) = mt*16+q*4+r, D col = nt*16+l15 (stream nt, point l15)
        #pragma unroll
        for (int mt = 0; mt < 2; mt++) {
            const int bc = wv * 64 + mt * 32 + q * 8;   // byte col of 4-neuron group
            v4f bb = bs[mt];
            float h0 = fast_tanh(acc[mt][0][0] + bb[0]);
            float h1 = fast_tanh(acc[mt][0][1] + bb[1]);
            float h2 = fast_tanh(acc[mt][0][2] + bb[2]);
            float h3 = fast_tanh(acc[mt][0][3] + bb[3]);
            float d0 = 1.0f - h0 * h0, d1 = 1.0f - h1 * h1;
            float d2 = 1.0f - h2 * h2, d3 = 1.0f - h3 * h3;
            uint2 w;
            w.x = pk2(h0, h1); w.y = pk2(h2, h3);
            *(uint2*)(&dst[swz(l15, bc)]) = w;
            #pragma unroll
            for (int s = 1; s < 4; s++) {
                w.x = pk2(d0 * acc[mt][s][0], d1 * acc[mt][s][1]);
                w.y = pk2(d2 * acc[mt][s][2], d3 * acc[mt][s][3]);
                *(uint2*)(&dst[swz(s * 16 + l15, bc)]) = w;
            }
        }
    };

    // ---- residual for point p = lane (wave 7 lanes 0..15) --------------------
    auto residual = [&](int tile, int par) -> float {
        const int gp = tile * TPTS + lane;
        if (gp >= npts) return 0.0f;
        const float* Yh = Y4[par][0][lane];
        const float* JX = Y4[par][1][lane];
        const float* JY = Y4[par][2][lane];
        const float* JT = Y4[par][3][lane];
        const float g1 = 1.5f;
        float rho = Yh[0] + b40, vx = Yh[1] + b41, vy = Yh[2] + b42;
        float Bx  = Yh[3] + b43, By = Yh[4] + b44, P  = Yh[5] + b45;
        float v2 = vx * vx + vy * vy;
        float dt_rho = JT[0];
        float dt_rhovx = dt_rho * vx + rho * JT[1];
        float dt_rhovy = dt_rho * vy + rho * JT[2];
        auto dE = [&](const float* J) {
            return J[5] * g1 + 0.5f * J[0] * v2 + rho * (vx * J[1] + vy * J[2]) + Bx * J[3] + By * J[4];
        };
        float dE_dx = dE(JX), dE_dy = dE(JY), dE_dt = dE(JT);
        float div_v = JX[1] + JY[2];
        float div_B = JX[3] + JY[4];
        float continuity = dt_rho + rho * div_v;
        float dPm_dx = JX[5] + Bx * JX[3] + By * JX[4];
        float dPm_dy = JY[5] + Bx * JY[3] + By * JY[4];
        float momentum_x = dt_rhovx + dPm_dx - (Bx * JX[3] + By * JY[3]);
        float momentum_y = dt_rhovy + dPm_dy - (Bx * JX[4] + By * JY[4]);
        auto dG = [&](const float* J) {
            return J[1] * By + vx * J[4] - J[2] * Bx - vy * J[3];
        };
        float induction_x = JT[3] + dG(JY);
        float induction_y = JT[4] - dG(JX);
        float E = P * g1 + 0.5f * rho * v2 + 0.5f * (Bx * Bx + By * By);
        float S = E + P + 0.5f * (Bx * Bx + By * By);
        float dS_dx = dE_dx + JX[5] + Bx * JX[3] + By * JX[4];
        float dS_dy = dE_dy + JY[5] + Bx * JY[3] + By * JY[4];
        float D = Bx * vx + By * vy;
        auto dD = [&](const float* J) {
            return J[3] * vx + Bx * J[1] + J[4] * vy + By * J[2];
        };
        float dFx_dx = dS_dx * vx + S * JX[1] - dD(JX) * Bx - D * JX[3];
        float dFy_dy = dS_dy * vy + S * JY[2] - dD(JY) * By - D * JY[4];
        float energy = dE_dt + dFx_dx + dFy_dy;
        return wt0 * continuity * continuity
             + wt1 * momentum_x * momentum_x
             + wt2_ * momentum_y * momentum_y
             + wt3_ * induction_x * induction_x
             + wt4_ * induction_y * induction_y
             + wt5 * energy * energy
             + wt6 * div_B * div_B;
    };

    const int ntiles = (npts + TPTS - 1) / TPTS;
    const int myblk  = blockIdx.x;
    const int nit    = (myblk < ntiles) ? ((ntiles - 1 - myblk) / GRIDB + 1) : 0;
    float vsum = 0.0f;

    if (nit > 0) do_l1(myblk, XinB[0]);   // prologue: L1 for first tile

    for (int i = 0; i < nit; i++) {
        const int tile = myblk + i * GRIDB;
        // phase 0: residual(t-2) on wave 7 + L1(t+1) — no barrier vs L2 below
        if (wv == 7 && lane < TPTS && i >= 2)
            vsum += residual(tile - 2 * GRIDB, i & 1);
        if (i + 1 < nit) do_l1(tile + GRIDB, XinB[(i + 1) & 1]);
        __syncthreads();                       // B1
        dense(XinB[i & 1], Xmid, w2f, bs2);    // L2
        __syncthreads();                       // B2
        dense(Xmid, Xout, w3f, bs3);           // L3
        __syncthreads();                       // B3
        if (wv < 4) {                          // L4: wave wv handles stream wv
            v4f a4 = {0.0f, 0.0f, 0.0f, 0.0f};
            #pragma unroll
            for (int kk = 0; kk < 8; kk++) {
                v8h A = *(const v8h*)(&W4s[(l15 << 9) + (((kk * 4 + q) ^ l15) << 4)]);
                const int rowB = wv * 16 + l15;
                v8h B = *(const v8h*)(&Xout[(rowB << 9) + ((((kk * 4 + q) ^ (rowB & 31)) << 4))]);
                a4 = __builtin_amdgcn_mfma_f32_16x16x32_bf16(A, B, a4, 0, 0, 0);
            }
            if (q < 2) {
                #pragma unroll
                for (int r = 0; r < 4; r++)
                    Y4[i & 1][wv][l15][q * 4 + r] = a4[r];
            }
        }
        // no trailing barrier: next-iter phase0 touches only Xin[other]/Y4[done]
    }

    // drain: residuals for the last two tiles
    __syncthreads();
    if (wv == 7 && lane < TPTS) {
        if (nit >= 2) vsum += residual(myblk + (nit - 2) * GRIDB, nit & 1);
        if (nit >= 1) vsum += residual(myblk + (nit - 1) * GRIDB, (nit - 1) & 1);
    }

    if (wv == 7) {
        #pragma unroll
        for (int off = 8; off >= 1; off >>= 1)
            vsum += __shfl_down(vsum, off, 64);
        if (lane == 0) atomicAdd(out, vsum * inv_n);
    }
}

extern "C" void kernel_launch(void* const* d_in, const int* in_sizes, int n_in,
                              void* d_out, int out_size, void* d_ws, size_t ws_size,
                              hipStream_t stream) {
    const float* coords = (const float*)d_in[0];
    const float* W1 = (const float*)d_in[1];
    const float* b1 = (const float*)d_in[2];
    const float* W2 = (const float*)d_in[3];
    const float* b2 = (const float*)d_in[4];
    const float* W3 = (const float*)d_in[5];
    const float* b3 = (const float*)d_in[6];
    const float* W4 = (const float*)d_in[7];
    const float* b4 = (const float*)d_in[8];
    const float* wts = (const float*)d_in[9];
    const int npts = in_sizes[0] / 3;

    ushort* Wt2 = (ushort*)d_ws;
    ushort* Wt3 = Wt2 + 65536;
    ushort* Wt4 = Wt3 + 65536;

    (void)hipMemsetAsync(d_out, 0, sizeof(float), stream);
    prep_weights<<<256, 256, 0, stream>>>(W2, W3, W4, Wt2, Wt3, Wt4);
    mhd_fused<<<GRIDB, 512, 0, stream>>>(coords, W1, b1, b2, b3, b4, wts,
                                         Wt2, Wt3, Wt4, (float*)d_out, npts, 1.0f / npts);
}